// Round 14
// baseline (598.664 us; speedup 1.0000x reference)
//
#include <hip/hip_runtime.h>
#include <hip/hip_bf16.h>
#include <hip/hip_cooperative_groups.h>

namespace cg = cooperative_groups;

#define V_IN 128
#define U_IN 64
#define HID 128
#define K1  (V_IN + HID + U_IN)   // 320

typedef __attribute__((ext_vector_type(8))) short bf16x8;
typedef __attribute__((ext_vector_type(4))) float f32x4;

static __device__ __forceinline__ unsigned short f2bf(float f) {
    __hip_bfloat16 h = __float2bfloat16(f);
    union { __hip_bfloat16 h; unsigned short u; } v; v.h = h;
    return v.u;
}
static __device__ __forceinline__ unsigned int f2bf2(float lo, float hi) {
    __hip_bfloat162 h2 = __float22bfloat162_rn(make_float2(lo, hi));  // v_cvt_pk_bf16_f32
    union { __hip_bfloat162 h; unsigned int u; } v; v.h = h2;
    return v.u;
}

// ---------- single cooperative CSR build ----------
// phases: (A) zero deg + W->bf16 transpose, (B) hist, (C) per-chunk sums,
// (D) scan + offsets/cur, (E) fill eidx. grid.sync() between phases.
__global__ __launch_bounds__(256) void csr_build(
    const float* __restrict__ W1, const float* __restrict__ W2,
    unsigned short* __restrict__ Wt1, unsigned short* __restrict__ Wt2,
    int* __restrict__ deg, int* __restrict__ cur,
    int* __restrict__ offsets, int* __restrict__ blockSums,
    int* __restrict__ eidx, const int* __restrict__ col,
    int N, int E, int NB)
{
    cg::grid_group grid = cg::this_grid();
    __shared__ int sdata[256];
    __shared__ int rdata[256];
    const int tid = threadIdx.x;
    const int gid = blockIdx.x * 256 + tid;
    const int gsz = gridDim.x * 256;

    // ---- A: zero deg + weight transpose/convert
    for (int i = gid; i < N; i += gsz) deg[i] = 0;
    for (int i = gid; i < HID * K1; i += gsz) {      // Wt1: [128][320]
        int c = i / K1, k = i - c * K1;
        Wt1[i] = f2bf(W1[(size_t)k * HID + c]);
    }
    for (int i = gid; i < HID * HID; i += gsz) {     // Wt2: [128][128]
        int c = i >> 7, k = i & 127;
        Wt2[i] = f2bf(W2[(size_t)k * HID + c]);
    }
    grid.sync();

    // ---- B: histogram
    for (int e = gid; e < E; e += gsz) atomicAdd(&deg[col[e]], 1);
    grid.sync();

    // ---- C: per-1024-chunk sums (blocks 0..NB-1)
    if ((int)blockIdx.x < NB) {
        int base = blockIdx.x * 1024;
        int s = 0;
        #pragma unroll
        for (int j = 0; j < 4; ++j) {
            int i = base + tid * 4 + j;
            if (i < N) s += deg[i];
        }
        sdata[tid] = s;
        __syncthreads();
        for (int off = 128; off > 0; off >>= 1) {
            if (tid < off) sdata[tid] += sdata[tid + off];
            __syncthreads();
        }
        if (tid == 0) blockSums[blockIdx.x] = sdata[0];
    }
    grid.sync();

    // ---- D: exclusive scan -> offsets, cur
    if ((int)blockIdx.x < NB) {
        int part = 0;
        for (int i = tid; i < (int)blockIdx.x; i += 256) part += blockSums[i];
        rdata[tid] = part;
        __syncthreads();
        for (int off = 128; off > 0; off >>= 1) {
            if (tid < off) rdata[tid] += rdata[tid + off];
            __syncthreads();
        }
        const int blockPrefix = rdata[0];

        int base = blockIdx.x * 1024;
        int loc[4];
        int s = 0;
        #pragma unroll
        for (int j = 0; j < 4; ++j) {
            int i = base + tid * 4 + j;
            loc[j] = (i < N) ? deg[i] : 0;
            s += loc[j];
        }
        int mine = s;
        sdata[tid] = s;
        __syncthreads();
        for (int off = 1; off < 256; off <<= 1) {
            int t = (tid >= off) ? sdata[tid - off] : 0;
            __syncthreads();
            sdata[tid] += t;
            __syncthreads();
        }
        int prefix = blockPrefix + sdata[tid] - mine;
        #pragma unroll
        for (int j = 0; j < 4; ++j) {
            int i = base + tid * 4 + j;
            if (i < N) { offsets[i] = prefix; cur[i] = prefix; prefix += loc[j]; }
        }
    }
    if (gid == 0) offsets[N] = E;
    grid.sync();

    // ---- E: fill eidx
    for (int e = gid; e < E; e += gsz) {
        int p = atomicAdd(&cur[col[e]], 1);
        eidx[p] = e;
    }
}

// ---------- fused gather + 2-layer MLP via bf16 MFMA (R13 structure) ----------
// block = 512 threads = 8 waves; wave w owns output cols [16w, 16w+15];
// ROWS = 32 nodes/block, two 16-row tiles per wave share its in-reg W frags.
// Gather: dynamic row queue, half-wave/row, ILP-4 walks, indices from LDS.
// R14: PLAIN loads on edge_attr (NT hint dropped — cross-replay L3 retention
// of edge_attr is worth ~140 MB/replay; NT discourages allocation).
#define ROWS 32
#define LDA_E 328
#define LDH_E 136
#define ECAP 1280

__global__ __launch_bounds__(512, 4) void mlp_mfma(
    const float* __restrict__ x,
    const float* __restrict__ edge_attr,
    const int*   __restrict__ offsets,
    const int*   __restrict__ eidx,
    const float* __restrict__ u,
    const int*   __restrict__ batch,
    const unsigned short* __restrict__ Wt1,
    const unsigned short* __restrict__ Wt2,
    const float* __restrict__ b1, const float* __restrict__ b2,
    float* __restrict__ out, int N)
{
    __shared__ __align__(16) unsigned short A[ROWS * LDA_E];
    __shared__ __align__(16) unsigned short H[ROWS * LDH_E];
    __shared__ int Eidx[ECAP];
    __shared__ int Soff[ROWS + 1];
    __shared__ int ticket;
    const int tid  = threadIdx.x;
    const int n0   = blockIdx.x * ROWS;
    const int lane = tid & 63;
    const int wave = tid >> 6;       // 0..7 = which 16-col slice
    const int l15  = lane & 15;
    const int lhi  = lane >> 4;      // 0..3
    const int wcol = wave * 16 + l15;

    // ---- stage offsets slice (33 ints) and this tile's eidx slice into LDS
    const int nEnd   = (n0 + ROWS < N) ? n0 + ROWS : N;
    if (tid <= ROWS) {
        int idx = n0 + tid;
        Soff[tid] = offsets[(idx < nEnd) ? idx : nEnd];
    }
    if (tid == 0) ticket = 0;
    const int s_base = offsets[n0];
    const int s_end  = offsets[nEnd];
    const int cnt    = (s_end - s_base < ECAP) ? s_end - s_base : ECAP;
    for (int i = tid; i < cnt; i += 512) Eidx[i] = eidx[s_base + i];

    // ---- stage x (32 float4 segs/row) and u (16 segs/row): 32*48 = 1536 tasks
    #pragma unroll
    for (int it = 0; it < 3; ++it) {
        int t   = tid + it * 512;
        int row = t / 48;
        int s   = t - row * 48;
        int n   = n0 + row;
        unsigned short* Arow = &A[row * LDA_E];
        float4 v = make_float4(0.f, 0.f, 0.f, 0.f);
        int colbase;
        if (s < 32) {                                // x: cols 0..127
            if (n < N) v = ((const float4*)(x + (size_t)n * V_IN))[s];
            colbase = s * 4;
        } else {                                     // u: cols 256..319
            if (n < N) {
                int b = batch[n];
                v = ((const float4*)(u + (size_t)b * U_IN))[s - 32];
            }
            colbase = V_IN + HID + (s - 32) * 4;
        }
        uint2 o; o.x = f2bf2(v.x, v.y); o.y = f2bf2(v.z, v.w);
        *(uint2*)&Arow[colbase] = o;
    }
    __syncthreads();   // Eidx, Soff, ticket visible

    // ---- gather agg into A cols 128..255: dynamic row queue, half-wave/row
    {
        const int c = tid & 31;
        for (;;) {
            int r;
            if (c == 0) r = atomicAdd(&ticket, 1);
            r = __shfl(r, 0, 32);                 // broadcast within half-wave
            if (r >= ROWS) break;
            int n = n0 + r;
            f32x4 a0 = {0.f, 0.f, 0.f, 0.f};
            f32x4 a1 = {0.f, 0.f, 0.f, 0.f};
            f32x4 a2 = {0.f, 0.f, 0.f, 0.f};
            f32x4 a3 = {0.f, 0.f, 0.f, 0.f};
            if (n < N) {
                int ls = Soff[r]     - s_base;
                int le = Soff[r + 1] - s_base;
                int j = ls;
                for (; j + 3 < le; j += 4) {
                    int e0, e1, e2, e3;
                    if (j + 3 < ECAP) {
                        e0 = Eidx[j];     e1 = Eidx[j + 1];
                        e2 = Eidx[j + 2]; e3 = Eidx[j + 3];
                    } else {
                        e0 = eidx[s_base + j];     e1 = eidx[s_base + j + 1];
                        e2 = eidx[s_base + j + 2]; e3 = eidx[s_base + j + 3];
                    }
                    f32x4 v0 = *((const f32x4*)(edge_attr + (size_t)e0 * HID) + c);
                    f32x4 v1 = *((const f32x4*)(edge_attr + (size_t)e1 * HID) + c);
                    f32x4 v2 = *((const f32x4*)(edge_attr + (size_t)e2 * HID) + c);
                    f32x4 v3 = *((const f32x4*)(edge_attr + (size_t)e3 * HID) + c);
                    a0 += v0; a1 += v1; a2 += v2; a3 += v3;
                }
                for (; j < le; ++j) {
                    int e0 = (j < ECAP) ? Eidx[j] : eidx[s_base + j];
                    a0 += *((const f32x4*)(edge_attr + (size_t)e0 * HID) + c);
                }
            }
            f32x4 asum = (a0 + a1) + (a2 + a3);
            uint2 o;
            o.x = f2bf2(asum[0], asum[1]);
            o.y = f2bf2(asum[2], asum[3]);
            *(uint2*)&A[r * LDA_E + V_IN + c * 4] = o;
        }
    }

    // ---- W fragments into registers (B-operand: col=l15, k contiguous)
    bf16x8 w1f[10], w2f[4];
    #pragma unroll
    for (int ks = 0; ks < 10; ++ks)
        w1f[ks] = *(const bf16x8*)(Wt1 + (size_t)wcol * K1 + ks * 32 + lhi * 8);
    #pragma unroll
    for (int ks = 0; ks < 4; ++ks)
        w2f[ks] = *(const bf16x8*)(Wt2 + (size_t)wcol * HID + ks * 32 + lhi * 8);
    const float b1v = b1[wcol];
    const float b2v = b2[wcol];

    __syncthreads();

    // ---- layer 1: two 16-row tiles share w1f
    f32x4 acc[2] = {{0.f, 0.f, 0.f, 0.f}, {0.f, 0.f, 0.f, 0.f}};
    #pragma unroll
    for (int ks = 0; ks < 10; ++ks) {
        #pragma unroll
        for (int h = 0; h < 2; ++h) {
            bf16x8 af = *(const bf16x8*)&A[(h * 16 + l15) * LDA_E + ks * 32 + lhi * 8];
            acc[h] = __builtin_amdgcn_mfma_f32_16x16x32_bf16(af, w1f[ks], acc[h], 0, 0, 0);
        }
    }
    // bias + relu -> H (D layout: row = lhi*4+r, col = l15 in wave's slice)
    #pragma unroll
    for (int h = 0; h < 2; ++h)
        #pragma unroll
        for (int r = 0; r < 4; ++r) {
            float hv = fmaxf(acc[h][r] + b1v, 0.f);
            H[(h * 16 + lhi * 4 + r) * LDH_E + wcol] = f2bf(hv);
        }
    __syncthreads();

    // ---- layer 2: two 16-row tiles share w2f
    f32x4 acc2[2] = {{0.f, 0.f, 0.f, 0.f}, {0.f, 0.f, 0.f, 0.f}};
    #pragma unroll
    for (int ks = 0; ks < 4; ++ks) {
        #pragma unroll
        for (int h = 0; h < 2; ++h) {
            bf16x8 hf = *(const bf16x8*)&H[(h * 16 + l15) * LDH_E + ks * 32 + lhi * 8];
            acc2[h] = __builtin_amdgcn_mfma_f32_16x16x32_bf16(hf, w2f[ks], acc2[h], 0, 0, 0);
        }
    }
    #pragma unroll
    for (int h = 0; h < 2; ++h)
        #pragma unroll
        for (int r = 0; r < 4; ++r) {
            int n = n0 + h * 16 + lhi * 4 + r;
            if (n < N) out[(size_t)n * HID + wcol] = acc2[h][r] + b2v;
        }
}

extern "C" void kernel_launch(void* const* d_in, const int* in_sizes, int n_in,
                              void* d_out, int out_size, void* d_ws, size_t ws_size,
                              hipStream_t stream) {
    const float* x          = (const float*)d_in[0];
    const int*   edge_index = (const int*)  d_in[1];
    const float* edge_attr  = (const float*)d_in[2];
    const float* u          = (const float*)d_in[3];
    const int*   batch      = (const int*)  d_in[4];
    const float* W1         = (const float*)d_in[5];
    const float* b1         = (const float*)d_in[6];
    const float* W2         = (const float*)d_in[7];
    const float* b2         = (const float*)d_in[8];
    float* out = (float*)d_out;

    const int N = in_sizes[0] / V_IN;
    const int E = in_sizes[1] / 2;
    const int* col = edge_index + E;   // row 1 = destination

    // ws layout
    unsigned short* Wt1  = (unsigned short*)d_ws;        // 320*128 bf16
    unsigned short* Wt2  = Wt1 + (size_t)K1 * HID;       // 128*128 bf16
    int* deg       = (int*)(Wt2 + (size_t)HID * HID);
    int* cur       = deg + N;
    int* offsets   = cur + N;
    int* blockSums = offsets + N + 1;
    int* eidx      = blockSums + 2048;

    int NB = (N + 1023) / 1024;
    int Nv = N, Ev = E;

    void* args[] = {
        (void*)&W1, (void*)&W2, (void*)&Wt1, (void*)&Wt2,
        (void*)&deg, (void*)&cur, (void*)&offsets, (void*)&blockSums,
        (void*)&eidx, (void*)&col, (void*)&Nv, (void*)&Ev, (void*)&NB
    };
    hipLaunchCooperativeKernel((const void*)csr_build,
                               dim3(1024), dim3(256), args, 0, stream);

    mlp_mfma<<<(N + ROWS - 1) / ROWS, 512, 0, stream>>>(
        x, edge_attr, offsets, eidx, u, batch, Wt1, Wt2, b1, b2, out, N);
}

// Round 15
// 211.902 us; speedup vs baseline: 2.8252x; 2.8252x over previous
//
#include <hip/hip_runtime.h>
#include <hip/hip_bf16.h>

#define V_IN 128
#define U_IN 64
#define HID 128
#define K1  (V_IN + HID + U_IN)   // 320

typedef __attribute__((ext_vector_type(8))) short bf16x8;
typedef __attribute__((ext_vector_type(4))) float f32x4;

static __device__ __forceinline__ unsigned short f2bf(float f) {
    __hip_bfloat16 h = __float2bfloat16(f);
    union { __hip_bfloat16 h; unsigned short u; } v; v.h = h;
    return v.u;
}
static __device__ __forceinline__ unsigned int f2bf2(float lo, float hi) {
    __hip_bfloat162 h2 = __float22bfloat162_rn(make_float2(lo, hi));  // v_cvt_pk_bf16_f32
    union { __hip_bfloat162 h; unsigned int u; } v; v.h = h2;
    return v.u;
}

// ---------- fused: zero deg + W1/W2 -> bf16 transposed ----------
__global__ __launch_bounds__(256) void zero_prep(
    const float* __restrict__ W1, const float* __restrict__ W2,
    unsigned short* __restrict__ Wt1, unsigned short* __restrict__ Wt2,
    int* __restrict__ deg, int N)
{
    int id = blockIdx.x * 256 + threadIdx.x;
    if (id < N) deg[id] = 0;
    if (id < HID * K1) {                     // Wt1: [128][320]
        int c = id / K1, k = id - c * K1;
        Wt1[id] = f2bf(W1[(size_t)k * HID + c]);
    }
    if (id < HID * HID) {                    // Wt2: [128][128]
        int c = id >> 7, k = id & 127;
        Wt2[id] = f2bf(W2[(size_t)k * HID + c]);
    }
}

// ---------- CSR build (5 small launches: grid.sync costs ~100us/sync on
// 8-XCD MI355X — R14's cooperative fusion was 471us vs ~30us for these) ----------

__global__ __launch_bounds__(256) void hist_kernel(
    const int* __restrict__ col, int* __restrict__ deg, int E)
{
    int e = blockIdx.x * 256 + threadIdx.x;
    if (e < E) atomicAdd(&deg[col[e]], 1);
}

__global__ __launch_bounds__(256) void scan_partial(
    const int* __restrict__ deg, int* __restrict__ blockSums, int N)
{
    __shared__ int sdata[256];
    int base = blockIdx.x * 1024;
    int tid  = threadIdx.x;
    int s = 0;
    #pragma unroll
    for (int j = 0; j < 4; ++j) {
        int i = base + tid * 4 + j;
        if (i < N) s += deg[i];
    }
    sdata[tid] = s;
    __syncthreads();
    for (int off = 128; off > 0; off >>= 1) {
        if (tid < off) sdata[tid] += sdata[tid + off];
        __syncthreads();
    }
    if (tid == 0) blockSums[blockIdx.x] = sdata[0];
}

// final: computes its own blockSums prefix (separate scan kernel folded in)
__global__ __launch_bounds__(256) void scan_final(
    const int* __restrict__ deg, const int* __restrict__ blockSums,
    int* __restrict__ offsets, int* __restrict__ cur, int N, int E)
{
    __shared__ int sdata[256];
    __shared__ int rdata[256];
    int tid = threadIdx.x;

    int part = 0;
    for (int i = tid; i < (int)blockIdx.x; i += 256) part += blockSums[i];
    rdata[tid] = part;
    __syncthreads();
    for (int off = 128; off > 0; off >>= 1) {
        if (tid < off) rdata[tid] += rdata[tid + off];
        __syncthreads();
    }
    const int blockPrefix = rdata[0];

    int base = blockIdx.x * 1024;
    int loc[4];
    int s = 0;
    #pragma unroll
    for (int j = 0; j < 4; ++j) {
        int i = base + tid * 4 + j;
        loc[j] = (i < N) ? deg[i] : 0;
        s += loc[j];
    }
    int mine = s;
    sdata[tid] = s;
    __syncthreads();
    for (int off = 1; off < 256; off <<= 1) {
        int t = (tid >= off) ? sdata[tid - off] : 0;
        __syncthreads();
        sdata[tid] += t;
        __syncthreads();
    }
    int prefix = blockPrefix + sdata[tid] - mine;
    #pragma unroll
    for (int j = 0; j < 4; ++j) {
        int i = base + tid * 4 + j;
        if (i < N) { offsets[i] = prefix; cur[i] = prefix; prefix += loc[j]; }
    }
    if (blockIdx.x == 0 && tid == 0) offsets[N] = E;
}

__global__ __launch_bounds__(256) void fill_kernel(
    const int* __restrict__ col, int* __restrict__ cur,
    int* __restrict__ eidx, int E)
{
    int e = blockIdx.x * 256 + threadIdx.x;
    if (e < E) {
        int p = atomicAdd(&cur[col[e]], 1);
        eidx[p] = e;
    }
}

// ---------- fused gather + 2-layer MLP via bf16 MFMA (R13 structure) ----------
// block = 512 threads = 8 waves; wave w owns output cols [16w, 16w+15];
// ROWS = 32 nodes/block, two 16-row tiles per wave share its in-reg W frags.
// Gather: dynamic row queue (LDS ticket), half-wave/row, ILP-4 walks, indices
// from LDS. R15: PLAIN loads on edge_attr (NT dropped — L3 retains ~140MB of
// edge_attr across replays per R12 FETCH counters; NT fights that).
#define ROWS 32
#define LDA_E 328
#define LDH_E 136
#define ECAP 1280

__global__ __launch_bounds__(512, 4) void mlp_mfma(
    const float* __restrict__ x,
    const float* __restrict__ edge_attr,
    const int*   __restrict__ offsets,
    const int*   __restrict__ eidx,
    const float* __restrict__ u,
    const int*   __restrict__ batch,
    const unsigned short* __restrict__ Wt1,
    const unsigned short* __restrict__ Wt2,
    const float* __restrict__ b1, const float* __restrict__ b2,
    float* __restrict__ out, int N)
{
    __shared__ __align__(16) unsigned short A[ROWS * LDA_E];
    __shared__ __align__(16) unsigned short H[ROWS * LDH_E];
    __shared__ int Eidx[ECAP];
    __shared__ int Soff[ROWS + 1];
    __shared__ int ticket;
    const int tid  = threadIdx.x;
    const int n0   = blockIdx.x * ROWS;
    const int lane = tid & 63;
    const int wave = tid >> 6;       // 0..7 = which 16-col slice
    const int l15  = lane & 15;
    const int lhi  = lane >> 4;      // 0..3
    const int wcol = wave * 16 + l15;

    // ---- stage offsets slice (33 ints) and this tile's eidx slice into LDS
    const int nEnd   = (n0 + ROWS < N) ? n0 + ROWS : N;
    if (tid <= ROWS) {
        int idx = n0 + tid;
        Soff[tid] = offsets[(idx < nEnd) ? idx : nEnd];
    }
    if (tid == 0) ticket = 0;
    const int s_base = offsets[n0];
    const int s_end  = offsets[nEnd];
    const int cnt    = (s_end - s_base < ECAP) ? s_end - s_base : ECAP;
    for (int i = tid; i < cnt; i += 512) Eidx[i] = eidx[s_base + i];

    // ---- stage x (32 float4 segs/row) and u (16 segs/row): 32*48 = 1536 tasks
    #pragma unroll
    for (int it = 0; it < 3; ++it) {
        int t   = tid + it * 512;
        int row = t / 48;
        int s   = t - row * 48;
        int n   = n0 + row;
        unsigned short* Arow = &A[row * LDA_E];
        float4 v = make_float4(0.f, 0.f, 0.f, 0.f);
        int colbase;
        if (s < 32) {                                // x: cols 0..127
            if (n < N) v = ((const float4*)(x + (size_t)n * V_IN))[s];
            colbase = s * 4;
        } else {                                     // u: cols 256..319
            if (n < N) {
                int b = batch[n];
                v = ((const float4*)(u + (size_t)b * U_IN))[s - 32];
            }
            colbase = V_IN + HID + (s - 32) * 4;
        }
        uint2 o; o.x = f2bf2(v.x, v.y); o.y = f2bf2(v.z, v.w);
        *(uint2*)&Arow[colbase] = o;
    }
    __syncthreads();   // Eidx, Soff, ticket visible

    // ---- gather agg into A cols 128..255: dynamic row queue, half-wave/row
    {
        const int c = tid & 31;
        for (;;) {
            int r;
            if (c == 0) r = atomicAdd(&ticket, 1);
            r = __shfl(r, 0, 32);                 // broadcast within half-wave
            if (r >= ROWS) break;
            int n = n0 + r;
            f32x4 a0 = {0.f, 0.f, 0.f, 0.f};
            f32x4 a1 = {0.f, 0.f, 0.f, 0.f};
            f32x4 a2 = {0.f, 0.f, 0.f, 0.f};
            f32x4 a3 = {0.f, 0.f, 0.f, 0.f};
            if (n < N) {
                int ls = Soff[r]     - s_base;
                int le = Soff[r + 1] - s_base;
                int j = ls;
                for (; j + 3 < le; j += 4) {
                    int e0, e1, e2, e3;
                    if (j + 3 < ECAP) {
                        e0 = Eidx[j];     e1 = Eidx[j + 1];
                        e2 = Eidx[j + 2]; e3 = Eidx[j + 3];
                    } else {
                        e0 = eidx[s_base + j];     e1 = eidx[s_base + j + 1];
                        e2 = eidx[s_base + j + 2]; e3 = eidx[s_base + j + 3];
                    }
                    f32x4 v0 = *((const f32x4*)(edge_attr + (size_t)e0 * HID) + c);
                    f32x4 v1 = *((const f32x4*)(edge_attr + (size_t)e1 * HID) + c);
                    f32x4 v2 = *((const f32x4*)(edge_attr + (size_t)e2 * HID) + c);
                    f32x4 v3 = *((const f32x4*)(edge_attr + (size_t)e3 * HID) + c);
                    a0 += v0; a1 += v1; a2 += v2; a3 += v3;
                }
                for (; j < le; ++j) {
                    int e0 = (j < ECAP) ? Eidx[j] : eidx[s_base + j];
                    a0 += *((const f32x4*)(edge_attr + (size_t)e0 * HID) + c);
                }
            }
            f32x4 asum = (a0 + a1) + (a2 + a3);
            uint2 o;
            o.x = f2bf2(asum[0], asum[1]);
            o.y = f2bf2(asum[2], asum[3]);
            *(uint2*)&A[r * LDA_E + V_IN + c * 4] = o;
        }
    }

    // ---- W fragments into registers (B-operand: col=l15, k contiguous)
    bf16x8 w1f[10], w2f[4];
    #pragma unroll
    for (int ks = 0; ks < 10; ++ks)
        w1f[ks] = *(const bf16x8*)(Wt1 + (size_t)wcol * K1 + ks * 32 + lhi * 8);
    #pragma unroll
    for (int ks = 0; ks < 4; ++ks)
        w2f[ks] = *(const bf16x8*)(Wt2 + (size_t)wcol * HID + ks * 32 + lhi * 8);
    const float b1v = b1[wcol];
    const float b2v = b2[wcol];

    __syncthreads();

    // ---- layer 1: two 16-row tiles share w1f
    f32x4 acc[2] = {{0.f, 0.f, 0.f, 0.f}, {0.f, 0.f, 0.f, 0.f}};
    #pragma unroll
    for (int ks = 0; ks < 10; ++ks) {
        #pragma unroll
        for (int h = 0; h < 2; ++h) {
            bf16x8 af = *(const bf16x8*)&A[(h * 16 + l15) * LDA_E + ks * 32 + lhi * 8];
            acc[h] = __builtin_amdgcn_mfma_f32_16x16x32_bf16(af, w1f[ks], acc[h], 0, 0, 0);
        }
    }
    // bias + relu -> H (D layout: row = lhi*4+r, col = l15 in wave's slice)
    #pragma unroll
    for (int h = 0; h < 2; ++h)
        #pragma unroll
        for (int r = 0; r < 4; ++r) {
            float hv = fmaxf(acc[h][r] + b1v, 0.f);
            H[(h * 16 + lhi * 4 + r) * LDH_E + wcol] = f2bf(hv);
        }
    __syncthreads();

    // ---- layer 2: two 16-row tiles share w2f
    f32x4 acc2[2] = {{0.f, 0.f, 0.f, 0.f}, {0.f, 0.f, 0.f, 0.f}};
    #pragma unroll
    for (int ks = 0; ks < 4; ++ks) {
        #pragma unroll
        for (int h = 0; h < 2; ++h) {
            bf16x8 hf = *(const bf16x8*)&H[(h * 16 + l15) * LDH_E + ks * 32 + lhi * 8];
            acc2[h] = __builtin_amdgcn_mfma_f32_16x16x32_bf16(hf, w2f[ks], acc2[h], 0, 0, 0);
        }
    }
    #pragma unroll
    for (int h = 0; h < 2; ++h)
        #pragma unroll
        for (int r = 0; r < 4; ++r) {
            int n = n0 + h * 16 + lhi * 4 + r;
            if (n < N) out[(size_t)n * HID + wcol] = acc2[h][r] + b2v;
        }
}

extern "C" void kernel_launch(void* const* d_in, const int* in_sizes, int n_in,
                              void* d_out, int out_size, void* d_ws, size_t ws_size,
                              hipStream_t stream) {
    const float* x          = (const float*)d_in[0];
    const int*   edge_index = (const int*)  d_in[1];
    const float* edge_attr  = (const float*)d_in[2];
    const float* u          = (const float*)d_in[3];
    const int*   batch      = (const int*)  d_in[4];
    const float* W1         = (const float*)d_in[5];
    const float* b1         = (const float*)d_in[6];
    const float* W2         = (const float*)d_in[7];
    const float* b2         = (const float*)d_in[8];
    float* out = (float*)d_out;

    const int N = in_sizes[0] / V_IN;
    const int E = in_sizes[1] / 2;
    const int* col = edge_index + E;   // row 1 = destination

    // ws layout
    unsigned short* Wt1  = (unsigned short*)d_ws;        // 320*128 bf16
    unsigned short* Wt2  = Wt1 + (size_t)K1 * HID;       // 128*128 bf16
    int* deg       = (int*)(Wt2 + (size_t)HID * HID);
    int* cur       = deg + N;
    int* offsets   = cur + N;
    int* blockSums = offsets + N + 1;
    int* eidx      = blockSums + 2048;

    const int NB = (N + 1023) / 1024;
    const int ZP = ((N > HID * K1 ? N : HID * K1) + 255) / 256;

    zero_prep   <<<ZP, 256, 0, stream>>>(W1, W2, Wt1, Wt2, deg, N);
    hist_kernel <<<(E + 255) / 256, 256, 0, stream>>>(col, deg, E);
    scan_partial<<<NB, 256, 0, stream>>>(deg, blockSums, N);
    scan_final  <<<NB, 256, 0, stream>>>(deg, blockSums, offsets, cur, N, E);
    fill_kernel <<<(E + 255) / 256, 256, 0, stream>>>(col, cur, eidx, E);

    mlp_mfma<<<(N + ROWS - 1) / ROWS, 512, 0, stream>>>(
        x, edge_attr, offsets, eidx, u, batch, Wt1, Wt2, b1, b2, out, N);
}

// Round 16
// 207.040 us; speedup vs baseline: 2.8915x; 1.0235x over previous
//
#include <hip/hip_runtime.h>
#include <hip/hip_bf16.h>

#define V_IN 128
#define U_IN 64
#define HID 128
#define K1  (V_IN + HID + U_IN)   // 320

typedef __attribute__((ext_vector_type(8))) short bf16x8;
typedef __attribute__((ext_vector_type(4))) float f32x4;

static __device__ __forceinline__ unsigned short f2bf(float f) {
    __hip_bfloat16 h = __float2bfloat16(f);
    union { __hip_bfloat16 h; unsigned short u; } v; v.h = h;
    return v.u;
}
static __device__ __forceinline__ unsigned int f2bf2(float lo, float hi) {
    __hip_bfloat162 h2 = __float22bfloat162_rn(make_float2(lo, hi));  // v_cvt_pk_bf16_f32
    union { __hip_bfloat162 h; unsigned int u; } v; v.h = h2;
    return v.u;
}

// ---------- fused: zero deg + W1/W2 -> bf16 transposed ----------
__global__ __launch_bounds__(256) void zero_prep(
    const float* __restrict__ W1, const float* __restrict__ W2,
    unsigned short* __restrict__ Wt1, unsigned short* __restrict__ Wt2,
    int* __restrict__ deg, int N)
{
    int id = blockIdx.x * 256 + threadIdx.x;
    if (id < N) deg[id] = 0;
    if (id < HID * K1) {                     // Wt1: [128][320]
        int c = id / K1, k = id - c * K1;
        Wt1[id] = f2bf(W1[(size_t)k * HID + c]);
    }
    if (id < HID * HID) {                    // Wt2: [128][128]
        int c = id >> 7, k = id & 127;
        Wt2[id] = f2bf(W2[(size_t)k * HID + c]);
    }
}

// ---------- CSR build (5 small launches; R14 showed grid.sync costs ~100us
// per sync on 8-XCD MI355X, so cooperative fusion is a dead end) ----------

__global__ __launch_bounds__(256) void hist_kernel(
    const int* __restrict__ col, int* __restrict__ deg, int E)
{
    int e = blockIdx.x * 256 + threadIdx.x;
    if (e < E) atomicAdd(&deg[col[e]], 1);
}

__global__ __launch_bounds__(256) void scan_partial(
    const int* __restrict__ deg, int* __restrict__ blockSums, int N)
{
    __shared__ int sdata[256];
    int base = blockIdx.x * 1024;
    int tid  = threadIdx.x;
    int s = 0;
    #pragma unroll
    for (int j = 0; j < 4; ++j) {
        int i = base + tid * 4 + j;
        if (i < N) s += deg[i];
    }
    sdata[tid] = s;
    __syncthreads();
    for (int off = 128; off > 0; off >>= 1) {
        if (tid < off) sdata[tid] += sdata[tid + off];
        __syncthreads();
    }
    if (tid == 0) blockSums[blockIdx.x] = sdata[0];
}

// final: computes its own blockSums prefix (separate scan kernel folded in)
__global__ __launch_bounds__(256) void scan_final(
    const int* __restrict__ deg, const int* __restrict__ blockSums,
    int* __restrict__ offsets, int* __restrict__ cur, int N, int E)
{
    __shared__ int sdata[256];
    __shared__ int rdata[256];
    int tid = threadIdx.x;

    int part = 0;
    for (int i = tid; i < (int)blockIdx.x; i += 256) part += blockSums[i];
    rdata[tid] = part;
    __syncthreads();
    for (int off = 128; off > 0; off >>= 1) {
        if (tid < off) rdata[tid] += rdata[tid + off];
        __syncthreads();
    }
    const int blockPrefix = rdata[0];

    int base = blockIdx.x * 1024;
    int loc[4];
    int s = 0;
    #pragma unroll
    for (int j = 0; j < 4; ++j) {
        int i = base + tid * 4 + j;
        loc[j] = (i < N) ? deg[i] : 0;
        s += loc[j];
    }
    int mine = s;
    sdata[tid] = s;
    __syncthreads();
    for (int off = 1; off < 256; off <<= 1) {
        int t = (tid >= off) ? sdata[tid - off] : 0;
        __syncthreads();
        sdata[tid] += t;
        __syncthreads();
    }
    int prefix = blockPrefix + sdata[tid] - mine;
    #pragma unroll
    for (int j = 0; j < 4; ++j) {
        int i = base + tid * 4 + j;
        if (i < N) { offsets[i] = prefix; cur[i] = prefix; prefix += loc[j]; }
    }
    if (blockIdx.x == 0 && tid == 0) offsets[N] = E;
}

__global__ __launch_bounds__(256) void fill_kernel(
    const int* __restrict__ col, int* __restrict__ cur,
    int* __restrict__ eidx, int E)
{
    int e = blockIdx.x * 256 + threadIdx.x;
    if (e < E) {
        int p = atomicAdd(&cur[col[e]], 1);
        eidx[p] = e;
    }
}

// ---------- fused gather + 2-layer MLP via bf16 MFMA (R13 = best known) ----------
// block = 512 threads = 8 waves; wave w owns output cols [16w, 16w+15];
// ROWS = 32 nodes/block, two 16-row tiles per wave share its in-reg W frags.
// Gather: dynamic row queue (LDS ticket), half-wave/row, ILP-4 walks, indices
// from LDS, NT loads on edge_attr (read-once per replay: keep it out of L2,
// preserving cache for eidx/offsets/x/out — R15 A/B: NT is worth ~12us).
#define ROWS 32
#define LDA_E 328
#define LDH_E 136
#define ECAP 1280

__global__ __launch_bounds__(512, 4) void mlp_mfma(
    const float* __restrict__ x,
    const float* __restrict__ edge_attr,
    const int*   __restrict__ offsets,
    const int*   __restrict__ eidx,
    const float* __restrict__ u,
    const int*   __restrict__ batch,
    const unsigned short* __restrict__ Wt1,
    const unsigned short* __restrict__ Wt2,
    const float* __restrict__ b1, const float* __restrict__ b2,
    float* __restrict__ out, int N)
{
    __shared__ __align__(16) unsigned short A[ROWS * LDA_E];
    __shared__ __align__(16) unsigned short H[ROWS * LDH_E];
    __shared__ int Eidx[ECAP];
    __shared__ int Soff[ROWS + 1];
    __shared__ int ticket;
    const int tid  = threadIdx.x;
    const int n0   = blockIdx.x * ROWS;
    const int lane = tid & 63;
    const int wave = tid >> 6;       // 0..7 = which 16-col slice
    const int l15  = lane & 15;
    const int lhi  = lane >> 4;      // 0..3
    const int wcol = wave * 16 + l15;

    // ---- stage offsets slice (33 ints) and this tile's eidx slice into LDS
    const int nEnd   = (n0 + ROWS < N) ? n0 + ROWS : N;
    if (tid <= ROWS) {
        int idx = n0 + tid;
        Soff[tid] = offsets[(idx < nEnd) ? idx : nEnd];
    }
    if (tid == 0) ticket = 0;
    const int s_base = offsets[n0];
    const int s_end  = offsets[nEnd];
    const int cnt    = (s_end - s_base < ECAP) ? s_end - s_base : ECAP;
    for (int i = tid; i < cnt; i += 512) Eidx[i] = eidx[s_base + i];

    // ---- stage x (32 float4 segs/row) and u (16 segs/row): 32*48 = 1536 tasks
    #pragma unroll
    for (int it = 0; it < 3; ++it) {
        int t   = tid + it * 512;
        int row = t / 48;
        int s   = t - row * 48;
        int n   = n0 + row;
        unsigned short* Arow = &A[row * LDA_E];
        float4 v = make_float4(0.f, 0.f, 0.f, 0.f);
        int colbase;
        if (s < 32) {                                // x: cols 0..127
            if (n < N) v = ((const float4*)(x + (size_t)n * V_IN))[s];
            colbase = s * 4;
        } else {                                     // u: cols 256..319
            if (n < N) {
                int b = batch[n];
                v = ((const float4*)(u + (size_t)b * U_IN))[s - 32];
            }
            colbase = V_IN + HID + (s - 32) * 4;
        }
        uint2 o; o.x = f2bf2(v.x, v.y); o.y = f2bf2(v.z, v.w);
        *(uint2*)&Arow[colbase] = o;
    }
    __syncthreads();   // Eidx, Soff, ticket visible

    // ---- gather agg into A cols 128..255: dynamic row queue, half-wave/row
    {
        const int c = tid & 31;
        for (;;) {
            int r;
            if (c == 0) r = atomicAdd(&ticket, 1);
            r = __shfl(r, 0, 32);                 // broadcast within half-wave
            if (r >= ROWS) break;
            int n = n0 + r;
            f32x4 a0 = {0.f, 0.f, 0.f, 0.f};
            f32x4 a1 = {0.f, 0.f, 0.f, 0.f};
            f32x4 a2 = {0.f, 0.f, 0.f, 0.f};
            f32x4 a3 = {0.f, 0.f, 0.f, 0.f};
            if (n < N) {
                int ls = Soff[r]     - s_base;
                int le = Soff[r + 1] - s_base;
                int j = ls;
                for (; j + 3 < le; j += 4) {
                    int e0, e1, e2, e3;
                    if (j + 3 < ECAP) {
                        e0 = Eidx[j];     e1 = Eidx[j + 1];
                        e2 = Eidx[j + 2]; e3 = Eidx[j + 3];
                    } else {
                        e0 = eidx[s_base + j];     e1 = eidx[s_base + j + 1];
                        e2 = eidx[s_base + j + 2]; e3 = eidx[s_base + j + 3];
                    }
                    f32x4 v0 = __builtin_nontemporal_load((const f32x4*)(edge_attr + (size_t)e0 * HID) + c);
                    f32x4 v1 = __builtin_nontemporal_load((const f32x4*)(edge_attr + (size_t)e1 * HID) + c);
                    f32x4 v2 = __builtin_nontemporal_load((const f32x4*)(edge_attr + (size_t)e2 * HID) + c);
                    f32x4 v3 = __builtin_nontemporal_load((const f32x4*)(edge_attr + (size_t)e3 * HID) + c);
                    a0 += v0; a1 += v1; a2 += v2; a3 += v3;
                }
                for (; j < le; ++j) {
                    int e0 = (j < ECAP) ? Eidx[j] : eidx[s_base + j];
                    a0 += __builtin_nontemporal_load((const f32x4*)(edge_attr + (size_t)e0 * HID) + c);
                }
            }
            f32x4 asum = (a0 + a1) + (a2 + a3);
            uint2 o;
            o.x = f2bf2(asum[0], asum[1]);
            o.y = f2bf2(asum[2], asum[3]);
            *(uint2*)&A[r * LDA_E + V_IN + c * 4] = o;
        }
    }

    // ---- W fragments into registers (B-operand: col=l15, k contiguous)
    bf16x8 w1f[10], w2f[4];
    #pragma unroll
    for (int ks = 0; ks < 10; ++ks)
        w1f[ks] = *(const bf16x8*)(Wt1 + (size_t)wcol * K1 + ks * 32 + lhi * 8);
    #pragma unroll
    for (int ks = 0; ks < 4; ++ks)
        w2f[ks] = *(const bf16x8*)(Wt2 + (size_t)wcol * HID + ks * 32 + lhi * 8);
    const float b1v = b1[wcol];
    const float b2v = b2[wcol];

    __syncthreads();

    // ---- layer 1: two 16-row tiles share w1f
    f32x4 acc[2] = {{0.f, 0.f, 0.f, 0.f}, {0.f, 0.f, 0.f, 0.f}};
    #pragma unroll
    for (int ks = 0; ks < 10; ++ks) {
        #pragma unroll
        for (int h = 0; h < 2; ++h) {
            bf16x8 af = *(const bf16x8*)&A[(h * 16 + l15) * LDA_E + ks * 32 + lhi * 8];
            acc[h] = __builtin_amdgcn_mfma_f32_16x16x32_bf16(af, w1f[ks], acc[h], 0, 0, 0);
        }
    }
    // bias + relu -> H (D layout: row = lhi*4+r, col = l15 in wave's slice)
    #pragma unroll
    for (int h = 0; h < 2; ++h)
        #pragma unroll
        for (int r = 0; r < 4; ++r) {
            float hv = fmaxf(acc[h][r] + b1v, 0.f);
            H[(h * 16 + lhi * 4 + r) * LDH_E + wcol] = f2bf(hv);
        }
    __syncthreads();

    // ---- layer 2: two 16-row tiles share w2f
    f32x4 acc2[2] = {{0.f, 0.f, 0.f, 0.f}, {0.f, 0.f, 0.f, 0.f}};
    #pragma unroll
    for (int ks = 0; ks < 4; ++ks) {
        #pragma unroll
        for (int h = 0; h < 2; ++h) {
            bf16x8 hf = *(const bf16x8*)&H[(h * 16 + l15) * LDH_E + ks * 32 + lhi * 8];
            acc2[h] = __builtin_amdgcn_mfma_f32_16x16x32_bf16(hf, w2f[ks], acc2[h], 0, 0, 0);
        }
    }
    #pragma unroll
    for (int h = 0; h < 2; ++h)
        #pragma unroll
        for (int r = 0; r < 4; ++r) {
            int n = n0 + h * 16 + lhi * 4 + r;
            if (n < N) out[(size_t)n * HID + wcol] = acc2[h][r] + b2v;
        }
}

extern "C" void kernel_launch(void* const* d_in, const int* in_sizes, int n_in,
                              void* d_out, int out_size, void* d_ws, size_t ws_size,
                              hipStream_t stream) {
    const float* x          = (const float*)d_in[0];
    const int*   edge_index = (const int*)  d_in[1];
    const float* edge_attr  = (const float*)d_in[2];
    const float* u          = (const float*)d_in[3];
    const int*   batch      = (const int*)  d_in[4];
    const float* W1         = (const float*)d_in[5];
    const float* b1         = (const float*)d_in[6];
    const float* W2         = (const float*)d_in[7];
    const float* b2         = (const float*)d_in[8];
    float* out = (float*)d_out;

    const int N = in_sizes[0] / V_IN;
    const int E = in_sizes[1] / 2;
    const int* col = edge_index + E;   // row 1 = destination

    // ws layout
    unsigned short* Wt1  = (unsigned short*)d_ws;        // 320*128 bf16
    unsigned short* Wt2  = Wt1 + (size_t)K1 * HID;       // 128*128 bf16
    int* deg       = (int*)(Wt2 + (size_t)HID * HID);
    int* cur       = deg + N;
    int* offsets   = cur + N;
    int* blockSums = offsets + N + 1;
    int* eidx      = blockSums + 2048;

    const int NB = (N + 1023) / 1024;
    const int ZP = ((N > HID * K1 ? N : HID * K1) + 255) / 256;

    zero_prep   <<<ZP, 256, 0, stream>>>(W1, W2, Wt1, Wt2, deg, N);
    hist_kernel <<<(E + 255) / 256, 256, 0, stream>>>(col, deg, E);
    scan_partial<<<NB, 256, 0, stream>>>(deg, blockSums, N);
    scan_final  <<<NB, 256, 0, stream>>>(deg, blockSums, offsets, cur, N, E);
    fill_kernel <<<(E + 255) / 256, 256, 0, stream>>>(col, cur, eidx, E);

    mlp_mfma<<<(N + ROWS - 1) / ROWS, 512, 0, stream>>>(
        x, edge_attr, offsets, eidx, u, batch, Wt1, Wt2, b1, b2, out, N);
}